// Round 1
// baseline (1196.920 us; speedup 1.0000x reference)
//
#include <hip/hip_runtime.h>
#include <hip/hip_bf16.h>
#include <stdint.h>

#define NTOK 32768
#define DIM  768
#define HID  256
#define NEXP 8

typedef float f32x4 __attribute__((ext_vector_type(4)));
typedef short s16x8 __attribute__((ext_vector_type(8)));

__device__ __forceinline__ unsigned short f2bf(float f) {
  union { float f; unsigned int u; } c; c.f = f;
  unsigned int r = c.u + 0x7fffu + ((c.u >> 16) & 1u);
  return (unsigned short)(r >> 16);
}

// ---------------- x fp32 -> bf16 ----------------
__global__ __launch_bounds__(256) void k_cvt_x(const float* __restrict__ x,
                                               unsigned short* __restrict__ xbf) {
  int i = (blockIdx.x * 256 + threadIdx.x) * 8;
  float4 a = *(const float4*)(x + i);
  float4 b = *(const float4*)(x + i + 4);
  unsigned int p0 = (unsigned int)f2bf(a.x) | ((unsigned int)f2bf(a.y) << 16);
  unsigned int p1 = (unsigned int)f2bf(a.z) | ((unsigned int)f2bf(a.w) << 16);
  unsigned int p2 = (unsigned int)f2bf(b.x) | ((unsigned int)f2bf(b.y) << 16);
  unsigned int p3 = (unsigned int)f2bf(b.z) | ((unsigned int)f2bf(b.w) << 16);
  int4 v; v.x = (int)p0; v.y = (int)p1; v.z = (int)p2; v.w = (int)p3;
  *(int4*)(xbf + i) = v;
}

// ---------------- W1 -> W1t [E][H][D], W2 -> W2t [E][D][H], bf16 ----------------
__global__ __launch_bounds__(256) void k_cvt_w(const float* __restrict__ W1,
                                               const float* __restrict__ W2,
                                               unsigned short* __restrict__ w1t,
                                               unsigned short* __restrict__ w2t) {
  int o = blockIdx.x * 256 + threadIdx.x;  // 0 .. E*H*D-1
  if (blockIdx.y == 0) {
    int e = o / (HID * DIM); int r = o % (HID * DIM);
    int h = r / DIM; int d = r % DIM;
    w1t[o] = f2bf(W1[(e * DIM + d) * HID + h]);
  } else {
    int e = o / (HID * DIM); int r = o % (HID * DIM);
    int d = r / HID; int h = r % HID;
    w2t[o] = f2bf(W2[(e * HID + h) * DIM + d]);
  }
}

// ---------------- gate layer 1: hg = relu(x @ Wg1 + bg1), fp32 SGEMM ----------------
// BM=128 tokens, BN=64 hidden, BK=16
__global__ __launch_bounds__(256) void k_gate1(const float* __restrict__ x,
                                               const float* __restrict__ wg1,
                                               const float* __restrict__ bg1,
                                               float* __restrict__ hg) {
  __shared__ __align__(16) float As[16][132];  // transposed A tile, padded
  __shared__ __align__(16) float Bs[16][64];
  int bm = blockIdx.x * 128;
  int bn = blockIdx.y * 64;
  int tid = threadIdx.x;
  int tx = tid & 15, ty = tid >> 4;
  f32x4 acc[8] = {};
  for (int k0 = 0; k0 < DIM; k0 += 16) {
#pragma unroll
    for (int l = 0; l < 2; ++l) {
      int i4 = tid + l * 256;          // 0..511 float4 tiles of A (128x16)
      int row = i4 >> 2;
      int kq = (i4 & 3) * 4;
      float4 v = *(const float4*)&x[(bm + row) * DIM + k0 + kq];
      As[kq + 0][row] = v.x; As[kq + 1][row] = v.y;
      As[kq + 2][row] = v.z; As[kq + 3][row] = v.w;
    }
    {
      int krow = tid >> 4;
      int c4 = (tid & 15) * 4;
      *(float4*)&Bs[krow][c4] = *(const float4*)&wg1[(k0 + krow) * HID + bn + c4];
    }
    __syncthreads();
#pragma unroll
    for (int kk = 0; kk < 16; ++kk) {
      f32x4 a0 = *(const f32x4*)&As[kk][ty * 8];
      f32x4 a1 = *(const f32x4*)&As[kk][ty * 8 + 4];
      f32x4 bv = *(const f32x4*)&Bs[kk][tx * 4];
#pragma unroll
      for (int i = 0; i < 4; ++i) acc[i]     += bv * a0[i];
#pragma unroll
      for (int i = 0; i < 4; ++i) acc[i + 4] += bv * a1[i];
    }
    __syncthreads();
  }
  f32x4 bias = *(const f32x4*)&bg1[bn + tx * 4];
#pragma unroll
  for (int i = 0; i < 8; ++i) {
    f32x4 v = acc[i] + bias;
#pragma unroll
    for (int j = 0; j < 4; ++j) v[j] = fmaxf(v[j], 0.f);
    *(f32x4*)&hg[(bm + ty * 8 + i) * HID + bn + tx * 4] = v;
  }
}

// ---------------- gate layer 2 + softmax + top2 + routing lists ----------------
__global__ __launch_bounds__(256) void k_gate2(const float* __restrict__ hg,
                                               const float* __restrict__ wg2,
                                               const float* __restrict__ bg2,
                                               float* __restrict__ gprob,
                                               int* __restrict__ cnt,
                                               int* __restrict__ lists,
                                               float* __restrict__ wts) {
  int tok = blockIdx.x * 4 + (threadIdx.x >> 6);
  int lane = threadIdx.x & 63;
  f32x4 h = *(const f32x4*)&hg[tok * HID + lane * 4];
  float wf[32];
#pragma unroll
  for (int q = 0; q < 8; ++q) *(f32x4*)&wf[q * 4] = *(const f32x4*)&wg2[lane * 32 + q * 4];
  float s[8];
#pragma unroll
  for (int e = 0; e < 8; ++e)
    s[e] = h[0] * wf[e] + h[1] * wf[8 + e] + h[2] * wf[16 + e] + h[3] * wf[24 + e];
#pragma unroll
  for (int off = 1; off < 64; off <<= 1) {
#pragma unroll
    for (int e = 0; e < 8; ++e) s[e] += __shfl_xor(s[e], off);
  }
#pragma unroll
  for (int e = 0; e < 8; ++e) s[e] += bg2[e];
  float m = s[0];
#pragma unroll
  for (int e = 1; e < 8; ++e) m = fmaxf(m, s[e]);
  float p[8]; float sum = 0.f;
#pragma unroll
  for (int e = 0; e < 8; ++e) { p[e] = expf(s[e] - m); sum += p[e]; }
  float inv = 1.f / sum;
#pragma unroll
  for (int e = 0; e < 8; ++e) p[e] *= inv;
  if (lane == 0) {
    f32x4 o0 = {p[0], p[1], p[2], p[3]};
    f32x4 o1 = {p[4], p[5], p[6], p[7]};
    *(f32x4*)&gprob[tok * 8] = o0;
    *(f32x4*)&gprob[tok * 8 + 4] = o1;
    int e1 = 0; float p1 = p[0];
#pragma unroll
    for (int e = 1; e < 8; ++e) if (p[e] > p1) { p1 = p[e]; e1 = e; }
    int e2 = -1; float p2 = -1.f;
#pragma unroll
    for (int e = 0; e < 8; ++e) if (e != e1 && p[e] > p2) { p2 = p[e]; e2 = e; }
    float rinv = 1.f / (p1 + p2);
    int pos1 = atomicAdd(&cnt[e1], 1);
    lists[e1 * NTOK + pos1] = tok; wts[e1 * NTOK + pos1] = p1 * rinv;
    int pos2 = atomicAdd(&cnt[e2], 1);
    lists[e2 * NTOK + pos2] = tok; wts[e2 * NTOK + pos2] = p2 * rinv;
  }
}

// ---------------- fused routed expert FFN ----------------
// block: 64 gathered tokens, 256 threads (4 waves). Phase1: h=relu(x@W1+b1) into LDS.
// Phase2: out = h@W2+b2, weighted atomicAdd into output.
__global__ __launch_bounds__(256) void k_expert(const unsigned short* __restrict__ xbf,
                                                const unsigned short* __restrict__ w1t,
                                                const unsigned short* __restrict__ w2t,
                                                const float* __restrict__ b1,
                                                const float* __restrict__ b2,
                                                const int* __restrict__ cnt,
                                                const int* __restrict__ lists,
                                                const float* __restrict__ wts,
                                                float* __restrict__ out) {
  int e = blockIdx.y;
  int c = cnt[e];
  int row0 = blockIdx.x * 64;
  if (row0 >= c) return;

  __shared__ __align__(16) unsigned short xs[64 * 64];    // 8KB  (swizzled)
  __shared__ __align__(16) unsigned short wsm[256 * 64];  // 32KB (swizzled)
  __shared__ __align__(16) unsigned short hs[64 * 256];   // 32KB (swizzled)
  __shared__ int stok[64];
  __shared__ float swt[64];

  int tid = threadIdx.x;
  int lane = tid & 63;
  int wid = tid >> 6;
  int ar = lane & 15;
  int kg = lane >> 4;  // 0..3

  if (tid < 64) {
    int r = row0 + tid;
    stok[tid] = (r < c) ? lists[e * NTOK + r] : lists[e * NTOK];
    swt[tid]  = (r < c) ? wts[e * NTOK + r] : 0.f;
  }
  __syncthreads();

  // per-thread x staging sources (row gather), 2 chunks of 16B each
  const unsigned short* xsrc[2];
#pragma unroll
  for (int q = 0; q < 2; ++q) {
    int ci = tid + q * 256;
    int row = ci >> 3, cb = ci & 7;
    xsrc[q] = xbf + stok[row] * DIM + ((cb ^ (row & 7)) * 8);
  }

  f32x4 acc[4][4] = {};

  // ---- phase 1: h = relu(x @ W1 + b1), K = 768 in steps of 64 ----
  for (int kt = 0; kt < DIM / 64; ++kt) {
    int4 vx[2], vw[8];
#pragma unroll
    for (int q = 0; q < 2; ++q) vx[q] = *(const int4*)(xsrc[q] + kt * 64);
#pragma unroll
    for (int q = 0; q < 8; ++q) {
      int ci = tid + q * 256;
      int row = ci >> 3, cb = ci & 7;
      vw[q] = *(const int4*)(w1t + (e * HID + row) * DIM + kt * 64 + ((cb ^ (row & 7)) * 8));
    }
#pragma unroll
    for (int q = 0; q < 2; ++q) *(int4*)&xs[(tid + q * 256) * 8] = vx[q];
#pragma unroll
    for (int q = 0; q < 8; ++q) *(int4*)&wsm[(tid + q * 256) * 8] = vw[q];
    __syncthreads();
#pragma unroll
    for (int ks = 0; ks < 2; ++ks) {
      int kc = ks * 4 + kg;
      s16x8 a[4], b[4];
#pragma unroll
      for (int m = 0; m < 4; ++m) {
        int row = m * 16 + ar;
        a[m] = *(const s16x8*)&xs[row * 64 + ((kc ^ (row & 7)) * 8)];
      }
#pragma unroll
      for (int n = 0; n < 4; ++n) {
        int row = wid * 64 + n * 16 + ar;
        b[n] = *(const s16x8*)&wsm[row * 64 + ((kc ^ (row & 7)) * 8)];
      }
#pragma unroll
      for (int m = 0; m < 4; ++m)
#pragma unroll
        for (int n = 0; n < 4; ++n)
          acc[m][n] = __builtin_amdgcn_mfma_f32_16x16x32_bf16(a[m], b[n], acc[m][n], 0, 0, 0);
    }
    __syncthreads();
  }

  // bias + relu -> hs (bf16, swizzled)
#pragma unroll
  for (int n = 0; n < 4; ++n) {
    int col = wid * 64 + n * 16 + ar;
    float bb = b1[e * HID + col];
#pragma unroll
    for (int m = 0; m < 4; ++m) {
#pragma unroll
      for (int r = 0; r < 4; ++r) {
        int tr = m * 16 + kg * 4 + r;
        float v = fmaxf(acc[m][n][r] + bb, 0.f);
        hs[tr * HID + (((col >> 3) ^ (tr & 7)) * 8) + (col & 7)] = f2bf(v);
      }
    }
  }
  __syncthreads();

  // ---- phase 2: out = h @ W2 + b2, 3 panels of 256 output cols, K = 256 ----
#pragma unroll 1
  for (int p = 0; p < 3; ++p) {
#pragma unroll
    for (int m = 0; m < 4; ++m)
#pragma unroll
      for (int n = 0; n < 4; ++n) acc[m][n] = (f32x4){0.f, 0.f, 0.f, 0.f};
    for (int kt2 = 0; kt2 < 4; ++kt2) {
      int4 vw[8];
#pragma unroll
      for (int q = 0; q < 8; ++q) {
        int ci = tid + q * 256;
        int row = ci >> 3, cb = ci & 7;
        vw[q] = *(const int4*)(w2t + (e * DIM + p * HID + row) * HID + kt2 * 64 + ((cb ^ (row & 7)) * 8));
      }
#pragma unroll
      for (int q = 0; q < 8; ++q) *(int4*)&wsm[(tid + q * 256) * 8] = vw[q];
      __syncthreads();
#pragma unroll
      for (int ks = 0; ks < 2; ++ks) {
        int kc = ks * 4 + kg;
        int kch = kt2 * 8 + kc;  // chunk within 256-wide hs row
        s16x8 a[4], b[4];
#pragma unroll
        for (int m = 0; m < 4; ++m) {
          int row = m * 16 + ar;
          a[m] = *(const s16x8*)&hs[row * HID + ((kch ^ (row & 7)) * 8)];
        }
#pragma unroll
        for (int n = 0; n < 4; ++n) {
          int row = wid * 64 + n * 16 + ar;
          b[n] = *(const s16x8*)&wsm[row * 64 + ((kc ^ (row & 7)) * 8)];
        }
#pragma unroll
        for (int m = 0; m < 4; ++m)
#pragma unroll
          for (int n = 0; n < 4; ++n)
            acc[m][n] = __builtin_amdgcn_mfma_f32_16x16x32_bf16(a[m], b[n], acc[m][n], 0, 0, 0);
      }
      __syncthreads();
    }
    // epilogue: weighted atomic accumulate
#pragma unroll
    for (int n = 0; n < 4; ++n) {
      int col = p * HID + wid * 64 + n * 16 + ar;
      float bb = b2[e * DIM + col];
#pragma unroll
      for (int m = 0; m < 4; ++m) {
#pragma unroll
        for (int r = 0; r < 4; ++r) {
          int tr = m * 16 + kg * 4 + r;
          float v = (acc[m][n][r] + bb) * swt[tr];
          atomicAdd(&out[stok[tr] * DIM + col], v);
        }
      }
    }
  }
}

extern "C" void kernel_launch(void* const* d_in, const int* in_sizes, int n_in,
                              void* d_out, int out_size, void* d_ws, size_t ws_size,
                              hipStream_t stream) {
  const float* x   = (const float*)d_in[0];
  const float* W1  = (const float*)d_in[1];
  const float* b1  = (const float*)d_in[2];
  const float* W2  = (const float*)d_in[3];
  const float* b2  = (const float*)d_in[4];
  const float* Wg1 = (const float*)d_in[5];
  const float* bg1 = (const float*)d_in[6];
  const float* Wg2 = (const float*)d_in[7];
  const float* bg2 = (const float*)d_in[8];
  float* out = (float*)d_out;                       // [N][768] then [N][8]
  float* gprob = out + (size_t)NTOK * DIM;

  char* ws = (char*)d_ws;
  size_t off = 0;
  auto alloc = [&](size_t bytes) { void* pp = ws + off; off += (bytes + 255) & ~(size_t)255; return pp; };
  unsigned short* xbf = (unsigned short*)alloc((size_t)NTOK * DIM * 2);
  unsigned short* w1t = (unsigned short*)alloc((size_t)NEXP * HID * DIM * 2);
  unsigned short* w2t = (unsigned short*)alloc((size_t)NEXP * DIM * HID * 2);
  float* hg = (float*)alloc((size_t)NTOK * HID * 4);
  int* cnt = (int*)alloc(NEXP * 4);
  int* lists = (int*)alloc((size_t)NEXP * NTOK * 4);
  float* wts = (float*)alloc((size_t)NEXP * NTOK * 4);

  hipMemsetAsync(d_out, 0, (size_t)NTOK * DIM * sizeof(float), stream);
  hipMemsetAsync(cnt, 0, NEXP * sizeof(int), stream);

  k_cvt_x<<<(NTOK * DIM) / (256 * 8), 256, 0, stream>>>(x, xbf);
  k_cvt_w<<<dim3((NEXP * HID * DIM) / 256, 2), 256, 0, stream>>>(W1, W2, w1t, w2t);
  k_gate1<<<dim3(NTOK / 128, HID / 64), 256, 0, stream>>>(x, Wg1, bg1, hg);
  k_gate2<<<NTOK / 4, 256, 0, stream>>>(hg, Wg2, bg2, gprob, cnt, lists, wts);
  k_expert<<<dim3(NTOK / 64, NEXP), 256, 0, stream>>>(xbf, w1t, w2t, b1, b2, cnt, lists, wts, out);
}

// Round 2
// 479.751 us; speedup vs baseline: 2.4949x; 2.4949x over previous
//
#include <hip/hip_runtime.h>
#include <hip/hip_bf16.h>
#include <stdint.h>

#define NTOK 32768
#define DIM  768
#define HID  256
#define NEXP 8

typedef float f32x4 __attribute__((ext_vector_type(4)));
typedef short s16x8 __attribute__((ext_vector_type(8)));

__device__ __forceinline__ unsigned short f2bf(float f) {
  union { float f; unsigned int u; } c; c.f = f;
  unsigned int r = c.u + 0x7fffu + ((c.u >> 16) & 1u);
  return (unsigned short)(r >> 16);
}

// ---------------- x fp32 -> bf16 ----------------
__global__ __launch_bounds__(256) void k_cvt_x(const float* __restrict__ x,
                                               unsigned short* __restrict__ xbf) {
  int i = (blockIdx.x * 256 + threadIdx.x) * 8;
  float4 a = *(const float4*)(x + i);
  float4 b = *(const float4*)(x + i + 4);
  unsigned int p0 = (unsigned int)f2bf(a.x) | ((unsigned int)f2bf(a.y) << 16);
  unsigned int p1 = (unsigned int)f2bf(a.z) | ((unsigned int)f2bf(a.w) << 16);
  unsigned int p2 = (unsigned int)f2bf(b.x) | ((unsigned int)f2bf(b.y) << 16);
  unsigned int p3 = (unsigned int)f2bf(b.z) | ((unsigned int)f2bf(b.w) << 16);
  int4 v; v.x = (int)p0; v.y = (int)p1; v.z = (int)p2; v.w = (int)p3;
  *(int4*)(xbf + i) = v;
}

// ---------------- W1 -> W1t [E][H][D], W2 -> W2t [E][D][H], bf16 ----------------
__global__ __launch_bounds__(256) void k_cvt_w(const float* __restrict__ W1,
                                               const float* __restrict__ W2,
                                               unsigned short* __restrict__ w1t,
                                               unsigned short* __restrict__ w2t) {
  int o = blockIdx.x * 256 + threadIdx.x;  // 0 .. E*H*D-1
  if (blockIdx.y == 0) {
    int e = o / (HID * DIM); int r = o % (HID * DIM);
    int h = r / DIM; int d = r % DIM;
    w1t[o] = f2bf(W1[(e * DIM + d) * HID + h]);
  } else {
    int e = o / (HID * DIM); int r = o % (HID * DIM);
    int d = r / HID; int h = r % HID;
    w2t[o] = f2bf(W2[(e * HID + h) * DIM + d]);
  }
}

// ---------------- gate layer 1: hg = relu(x @ Wg1 + bg1), fp32 SGEMM ----------------
// BM=128 tokens, BN=64 hidden, BK=16
__global__ __launch_bounds__(256) void k_gate1(const float* __restrict__ x,
                                               const float* __restrict__ wg1,
                                               const float* __restrict__ bg1,
                                               float* __restrict__ hg) {
  __shared__ __align__(16) float As[16][132];  // transposed A tile, padded
  __shared__ __align__(16) float Bs[16][64];
  int bm = blockIdx.x * 128;
  int bn = blockIdx.y * 64;
  int tid = threadIdx.x;
  int tx = tid & 15, ty = tid >> 4;
  f32x4 acc[8] = {};
  for (int k0 = 0; k0 < DIM; k0 += 16) {
#pragma unroll
    for (int l = 0; l < 2; ++l) {
      int i4 = tid + l * 256;          // 0..511 float4 tiles of A (128x16)
      int row = i4 >> 2;
      int kq = (i4 & 3) * 4;
      float4 v = *(const float4*)&x[(bm + row) * DIM + k0 + kq];
      As[kq + 0][row] = v.x; As[kq + 1][row] = v.y;
      As[kq + 2][row] = v.z; As[kq + 3][row] = v.w;
    }
    {
      int krow = tid >> 4;
      int c4 = (tid & 15) * 4;
      *(float4*)&Bs[krow][c4] = *(const float4*)&wg1[(k0 + krow) * HID + bn + c4];
    }
    __syncthreads();
#pragma unroll
    for (int kk = 0; kk < 16; ++kk) {
      f32x4 a0 = *(const f32x4*)&As[kk][ty * 8];
      f32x4 a1 = *(const f32x4*)&As[kk][ty * 8 + 4];
      f32x4 bv = *(const f32x4*)&Bs[kk][tx * 4];
#pragma unroll
      for (int i = 0; i < 4; ++i) acc[i]     += bv * a0[i];
#pragma unroll
      for (int i = 0; i < 4; ++i) acc[i + 4] += bv * a1[i];
    }
    __syncthreads();
  }
  f32x4 bias = *(const f32x4*)&bg1[bn + tx * 4];
#pragma unroll
  for (int i = 0; i < 8; ++i) {
    f32x4 v = acc[i] + bias;
#pragma unroll
    for (int j = 0; j < 4; ++j) v[j] = fmaxf(v[j], 0.f);
    *(f32x4*)&hg[(bm + ty * 8 + i) * HID + bn + tx * 4] = v;
  }
}

// ---------------- gate layer 2 + softmax + top2 + routing lists ----------------
// Thread-per-token, 256 tokens/block. wg2 rows are wave-uniform -> scalar loads.
// Counts aggregate in LDS; 8 global atomics per block onto 128B-padded counters.
__global__ __launch_bounds__(256) void k_gate2(const float* __restrict__ hg,
                                               const float* __restrict__ wg2,
                                               const float* __restrict__ bg2,
                                               float* __restrict__ gprob,
                                               int* __restrict__ cnt,     // stride 32
                                               int* __restrict__ lists,
                                               float* __restrict__ wts) {
  __shared__ int lcnt[8];
  __shared__ int sbase[8];
  __shared__ int se1[256], se2[256], sp1[256], sp2[256];
  __shared__ float sw1[256], sw2[256];
  int tid = threadIdx.x;
  if (tid < 8) lcnt[tid] = 0;
  __syncthreads();

  int tok = blockIdx.x * 256 + tid;
  const float* hrow = hg + (size_t)tok * HID;

  float s[8];
#pragma unroll
  for (int e = 0; e < 8; ++e) s[e] = bg2[e];
#pragma unroll 8
  for (int j = 0; j < 64; ++j) {
    f32x4 hv = *(const f32x4*)(hrow + j * 4);
#pragma unroll
    for (int i = 0; i < 4; ++i) {
      const float* wr = wg2 + (j * 4 + i) * 8;  // uniform across wave -> SGPR
#pragma unroll
      for (int e = 0; e < 8; ++e) s[e] += hv[i] * wr[e];
    }
  }

  float m = s[0];
#pragma unroll
  for (int e = 1; e < 8; ++e) m = fmaxf(m, s[e]);
  float p[8]; float sum = 0.f;
#pragma unroll
  for (int e = 0; e < 8; ++e) { p[e] = expf(s[e] - m); sum += p[e]; }
  float inv = 1.f / sum;
#pragma unroll
  for (int e = 0; e < 8; ++e) p[e] *= inv;

  f32x4 o0 = {p[0], p[1], p[2], p[3]};
  f32x4 o1 = {p[4], p[5], p[6], p[7]};
  *(f32x4*)&gprob[(size_t)tok * 8] = o0;
  *(f32x4*)&gprob[(size_t)tok * 8 + 4] = o1;

  int e1 = 0; float p1 = p[0];
#pragma unroll
  for (int e = 1; e < 8; ++e) if (p[e] > p1) { p1 = p[e]; e1 = e; }
  int e2 = -1; float p2 = -1.f;
#pragma unroll
  for (int e = 0; e < 8; ++e) if (e != e1 && p[e] > p2) { p2 = p[e]; e2 = e; }
  float rinv = 1.f / (p1 + p2);

  int pos1 = atomicAdd(&lcnt[e1], 1);
  int pos2 = atomicAdd(&lcnt[e2], 1);
  se1[tid] = e1; sp1[tid] = pos1; sw1[tid] = p1 * rinv;
  se2[tid] = e2; sp2[tid] = pos2; sw2[tid] = p2 * rinv;
  __syncthreads();

  if (tid < 8) sbase[tid] = atomicAdd(&cnt[tid * 32], lcnt[tid]);
  __syncthreads();

  int a1i = sbase[se1[tid]] + sp1[tid];
  lists[se1[tid] * NTOK + a1i] = tok; wts[se1[tid] * NTOK + a1i] = sw1[tid];
  int a2i = sbase[se2[tid]] + sp2[tid];
  lists[se2[tid] * NTOK + a2i] = tok; wts[se2[tid] * NTOK + a2i] = sw2[tid];
}

// ---------------- fused routed expert FFN ----------------
// block: 64 gathered tokens, 256 threads (4 waves). Phase1: h=relu(x@W1+b1) into LDS.
// Phase2: out = h@W2+b2, weighted atomicAdd into output.
__global__ __launch_bounds__(256) void k_expert(const unsigned short* __restrict__ xbf,
                                                const unsigned short* __restrict__ w1t,
                                                const unsigned short* __restrict__ w2t,
                                                const float* __restrict__ b1,
                                                const float* __restrict__ b2,
                                                const int* __restrict__ cnt,
                                                const int* __restrict__ lists,
                                                const float* __restrict__ wts,
                                                float* __restrict__ out) {
  int e = blockIdx.y;
  int c = cnt[e * 32];
  int row0 = blockIdx.x * 64;
  if (row0 >= c) return;

  __shared__ __align__(16) unsigned short xs[64 * 64];    // 8KB  (swizzled)
  __shared__ __align__(16) unsigned short wsm[256 * 64];  // 32KB (swizzled)
  __shared__ __align__(16) unsigned short hs[64 * 256];   // 32KB (swizzled)
  __shared__ int stok[64];
  __shared__ float swt[64];

  int tid = threadIdx.x;
  int lane = tid & 63;
  int wid = tid >> 6;
  int ar = lane & 15;
  int kg = lane >> 4;  // 0..3

  if (tid < 64) {
    int r = row0 + tid;
    stok[tid] = (r < c) ? lists[e * NTOK + r] : lists[e * NTOK];
    swt[tid]  = (r < c) ? wts[e * NTOK + r] : 0.f;
  }
  __syncthreads();

  // per-thread x staging sources (row gather), 2 chunks of 16B each
  const unsigned short* xsrc[2];
#pragma unroll
  for (int q = 0; q < 2; ++q) {
    int ci = tid + q * 256;
    int row = ci >> 3, cb = ci & 7;
    xsrc[q] = xbf + stok[row] * DIM + ((cb ^ (row & 7)) * 8);
  }

  f32x4 acc[4][4] = {};

  // ---- phase 1: h = relu(x @ W1 + b1), K = 768 in steps of 64 ----
  for (int kt = 0; kt < DIM / 64; ++kt) {
    int4 vx[2], vw[8];
#pragma unroll
    for (int q = 0; q < 2; ++q) vx[q] = *(const int4*)(xsrc[q] + kt * 64);
#pragma unroll
    for (int q = 0; q < 8; ++q) {
      int ci = tid + q * 256;
      int row = ci >> 3, cb = ci & 7;
      vw[q] = *(const int4*)(w1t + (e * HID + row) * DIM + kt * 64 + ((cb ^ (row & 7)) * 8));
    }
#pragma unroll
    for (int q = 0; q < 2; ++q) *(int4*)&xs[(tid + q * 256) * 8] = vx[q];
#pragma unroll
    for (int q = 0; q < 8; ++q) *(int4*)&wsm[(tid + q * 256) * 8] = vw[q];
    __syncthreads();
#pragma unroll
    for (int ks = 0; ks < 2; ++ks) {
      int kc = ks * 4 + kg;
      s16x8 a[4], b[4];
#pragma unroll
      for (int m = 0; m < 4; ++m) {
        int row = m * 16 + ar;
        a[m] = *(const s16x8*)&xs[row * 64 + ((kc ^ (row & 7)) * 8)];
      }
#pragma unroll
      for (int n = 0; n < 4; ++n) {
        int row = wid * 64 + n * 16 + ar;
        b[n] = *(const s16x8*)&wsm[row * 64 + ((kc ^ (row & 7)) * 8)];
      }
#pragma unroll
      for (int m = 0; m < 4; ++m)
#pragma unroll
        for (int n = 0; n < 4; ++n)
          acc[m][n] = __builtin_amdgcn_mfma_f32_16x16x32_bf16(a[m], b[n], acc[m][n], 0, 0, 0);
    }
    __syncthreads();
  }

  // bias + relu -> hs (bf16, swizzled)
#pragma unroll
  for (int n = 0; n < 4; ++n) {
    int col = wid * 64 + n * 16 + ar;
    float bb = b1[e * HID + col];
#pragma unroll
    for (int m = 0; m < 4; ++m) {
#pragma unroll
      for (int r = 0; r < 4; ++r) {
        int tr = m * 16 + kg * 4 + r;
        float v = fmaxf(acc[m][n][r] + bb, 0.f);
        hs[tr * HID + (((col >> 3) ^ (tr & 7)) * 8) + (col & 7)] = f2bf(v);
      }
    }
  }
  __syncthreads();

  // ---- phase 2: out = h @ W2 + b2, 3 panels of 256 output cols, K = 256 ----
#pragma unroll 1
  for (int p = 0; p < 3; ++p) {
#pragma unroll
    for (int m = 0; m < 4; ++m)
#pragma unroll
      for (int n = 0; n < 4; ++n) acc[m][n] = (f32x4){0.f, 0.f, 0.f, 0.f};
    for (int kt2 = 0; kt2 < 4; ++kt2) {
      int4 vw[8];
#pragma unroll
      for (int q = 0; q < 8; ++q) {
        int ci = tid + q * 256;
        int row = ci >> 3, cb = ci & 7;
        vw[q] = *(const int4*)(w2t + (e * DIM + p * HID + row) * HID + kt2 * 64 + ((cb ^ (row & 7)) * 8));
      }
#pragma unroll
      for (int q = 0; q < 8; ++q) *(int4*)&wsm[(tid + q * 256) * 8] = vw[q];
      __syncthreads();
#pragma unroll
      for (int ks = 0; ks < 2; ++ks) {
        int kc = ks * 4 + kg;
        int kch = kt2 * 8 + kc;  // chunk within 256-wide hs row
        s16x8 a[4], b[4];
#pragma unroll
        for (int m = 0; m < 4; ++m) {
          int row = m * 16 + ar;
          a[m] = *(const s16x8*)&hs[row * HID + ((kch ^ (row & 7)) * 8)];
        }
#pragma unroll
        for (int n = 0; n < 4; ++n) {
          int row = wid * 64 + n * 16 + ar;
          b[n] = *(const s16x8*)&wsm[row * 64 + ((kc ^ (row & 7)) * 8)];
        }
#pragma unroll
        for (int m = 0; m < 4; ++m)
#pragma unroll
          for (int n = 0; n < 4; ++n)
            acc[m][n] = __builtin_amdgcn_mfma_f32_16x16x32_bf16(a[m], b[n], acc[m][n], 0, 0, 0);
      }
      __syncthreads();
    }
    // epilogue: weighted atomic accumulate
#pragma unroll
    for (int n = 0; n < 4; ++n) {
      int col = p * HID + wid * 64 + n * 16 + ar;
      float bb = b2[e * DIM + col];
#pragma unroll
      for (int m = 0; m < 4; ++m) {
#pragma unroll
        for (int r = 0; r < 4; ++r) {
          int tr = m * 16 + kg * 4 + r;
          float v = (acc[m][n][r] + bb) * swt[tr];
          atomicAdd(&out[stok[tr] * DIM + col], v);
        }
      }
    }
  }
}

extern "C" void kernel_launch(void* const* d_in, const int* in_sizes, int n_in,
                              void* d_out, int out_size, void* d_ws, size_t ws_size,
                              hipStream_t stream) {
  const float* x   = (const float*)d_in[0];
  const float* W1  = (const float*)d_in[1];
  const float* b1  = (const float*)d_in[2];
  const float* W2  = (const float*)d_in[3];
  const float* b2  = (const float*)d_in[4];
  const float* Wg1 = (const float*)d_in[5];
  const float* bg1 = (const float*)d_in[6];
  const float* Wg2 = (const float*)d_in[7];
  const float* bg2 = (const float*)d_in[8];
  float* out = (float*)d_out;                       // [N][768] then [N][8]
  float* gprob = out + (size_t)NTOK * DIM;

  char* ws = (char*)d_ws;
  size_t off = 0;
  auto alloc = [&](size_t bytes) { void* pp = ws + off; off += (bytes + 255) & ~(size_t)255; return pp; };
  unsigned short* xbf = (unsigned short*)alloc((size_t)NTOK * DIM * 2);
  unsigned short* w1t = (unsigned short*)alloc((size_t)NEXP * HID * DIM * 2);
  unsigned short* w2t = (unsigned short*)alloc((size_t)NEXP * DIM * HID * 2);
  float* hg = (float*)alloc((size_t)NTOK * HID * 4);
  int* cnt = (int*)alloc(NEXP * 32 * 4);            // 128B-padded counters
  int* lists = (int*)alloc((size_t)NEXP * NTOK * 4);
  float* wts = (float*)alloc((size_t)NEXP * NTOK * 4);

  hipMemsetAsync(d_out, 0, (size_t)NTOK * DIM * sizeof(float), stream);
  hipMemsetAsync(cnt, 0, NEXP * 32 * sizeof(int), stream);

  k_cvt_x<<<(NTOK * DIM) / (256 * 8), 256, 0, stream>>>(x, xbf);
  k_cvt_w<<<dim3((NEXP * HID * DIM) / 256, 2), 256, 0, stream>>>(W1, W2, w1t, w2t);
  k_gate1<<<dim3(NTOK / 128, HID / 64), 256, 0, stream>>>(x, Wg1, bg1, hg);
  k_gate2<<<NTOK / 256, 256, 0, stream>>>(hg, Wg2, bg2, gprob, cnt, lists, wts);
  k_expert<<<dim3(NTOK / 64, NEXP), 256, 0, stream>>>(xbf, w1t, w2t, b1, b2, cnt, lists, wts, out);
}